// Round 6
// baseline (202.447 us; speedup 1.0000x reference)
//
#include <hip/hip_runtime.h>
#include <math.h>

typedef __attribute__((ext_vector_type(8))) short short8;
typedef __attribute__((ext_vector_type(16))) float f32x16;
typedef __attribute__((ext_vector_type(2))) unsigned uintx2;

#define XS_STRIDE 72   // shorts per (row,col) cell: 64 ci + 8 pad -> 144 B, 16B-aligned
#define NROWS 10       // rows staged per strip: i0-1 .. i0+8

__device__ __forceinline__ short f2bf(float f) {
    union { float f; unsigned u; } v; v.f = f;
    unsigned r = (v.u + 0x7FFFu + ((v.u >> 16) & 1u)) >> 16;
    return (short)r;
}

// packed f32x2 -> bf16x2 (RNE on gfx950)
__device__ __forceinline__ unsigned cvt_pk_bf16(float lo, float hi) {
    unsigned r;
    asm("v_cvt_pk_bf16_f32 %0, %1, %2" : "=v"(r) : "v"(lo), "v"(hi));
    return r;
}

// Barrier draining LDS ops only (no vmcnt(0) like __syncthreads).
__device__ __forceinline__ void bar_lds() {
    asm volatile("s_waitcnt lgkmcnt(0)" ::: "memory");
    __builtin_amdgcn_s_barrier();
}

// Build weight A-fragments (wfrag[p][q][lane][j], p=ph*2+pw, q=tap*4+ci_blk);
// tail block zeroes the 16 per-image completion counters.
__global__ void prep(const float* __restrict__ w, short* __restrict__ wfrag,
                     unsigned* __restrict__ ctr) {
    if (blockIdx.x >= 128) {
        if (threadIdx.x < 16) ctr[threadIdx.x] = 0u;
        return;
    }
    int idx = blockIdx.x * 256 + threadIdx.x;   // 0 .. 32767
    int j    = idx & 7;
    int lane = (idx >> 3) & 63;
    int q    = (idx >> 9) & 15;
    int p    = idx >> 13;
    int co = lane & 31, hf = lane >> 5;
    int ci = (q & 3) * 16 + hf * 8 + j;
    int tq = q >> 2, a = tq >> 1, b = tq & 1;
    int ph = p >> 1, pw = p & 1;
    int kh = 2 * a + 1 - ph, kw = 2 * b + 1 - pw;
    wfrag[idx] = f2bf(w[((ci * 32 + co) * 4 + kh) * 4 + kw]);
}

// Block = (n, col quarter jq [32 cols], row strip st [8 input rows]).
// Staging: core rows first (depth-4 register pipeline, ~2.5 latency
// exposures), halo gathers issued AFTER all row loads (FIFO vmcnt: gathers
// no longer block the row pipeline), af/cb last (drained by barrier+compute).
// Then the barrier-free 4-step MFMA body (both row-pairs interleaved,
// shared middle row). Epilogue: non-atomic strip partials; the 64th block
// of each image sums its 16 strips and applies GELU+bias (fused finalize).
__global__ __launch_bounds__(256, 3) void convt_mfma(
    const float* __restrict__ x, const short* __restrict__ wfrag,
    const float* __restrict__ conv_b, float* __restrict__ partials,
    unsigned* __restrict__ ctr, const float* __restrict__ bias,
    float* __restrict__ out)
{
    __shared__ short xs[NROWS][34][XS_STRIDE];   // 48,960 B
    __shared__ float minbuf[4][32];
    __shared__ unsigned lastf;

    // XCD-aware bijective swizzle (1024 % 8 == 0)
    int blk = ((blockIdx.x & 7) << 7) | (blockIdx.x >> 3);
    const int jq = blk & 3, st = (blk >> 2) & 15, n = blk >> 6;
    const int t  = threadIdx.x;
    const int i0 = st * 8;

    const int wv = t >> 6, lane = t & 63;    // wave = output parity (ph,pw)
    const int ph = wv >> 1, pw = wv & 1;
    const int ln = lane & 31, half = lane >> 5;

    const float* xn = x + (size_t)n * 64 * 128 * 128;
    const int col  = t & 31;
    const int cib  = (t >> 5) * 8;
    const int gcol = jq * 32 + col;

    // ---- staging: core rows first, depth-4 pipeline ----
    float pf0[8], pf1[8], pf2[8], pf3[8];
    auto load_row = [&](int r, float* dst) {
        int gi = i0 - 1 + r;
        bool rowok = (unsigned)gi < 128u;
        int gic = rowok ? gi : 0;
        const float* px = xn + ((size_t)cib * 128 + gic) * 128 + gcol;
        #pragma unroll
        for (int c = 0; c < 8; ++c) dst[c] = rowok ? px[c * 16384] : 0.f;
    };
    auto write_row = [&](int r, const float* src) {
        uintx2 u0, u1;
        u0.x = cvt_pk_bf16(src[0], src[1]); u0.y = cvt_pk_bf16(src[2], src[3]);
        u1.x = cvt_pk_bf16(src[4], src[5]); u1.y = cvt_pk_bf16(src[6], src[7]);
        *(uintx2*)&xs[r][col + 1][cib]     = u0;
        *(uintx2*)&xs[r][col + 1][cib + 4] = u1;
    };
    load_row(0, pf0); load_row(1, pf1); load_row(2, pf2); load_row(3, pf3);
    write_row(0, pf0); load_row(4, pf0);
    write_row(1, pf1); load_row(5, pf1);
    write_row(2, pf2); load_row(6, pf2);
    write_row(3, pf3); load_row(7, pf3);
    write_row(4, pf0); load_row(8, pf0);
    write_row(5, pf1); load_row(9, pf1);
    write_row(6, pf2);
    write_row(7, pf3);
    write_row(8, pf0);
    write_row(9, pf1);

    // halo gathers (10 rows x 2 sides x 64 ci): issued after all row loads
    float hv[5];
    #pragma unroll
    for (int q = 0; q < 5; ++q) {
        int idx = q * 256 + t;
        int r = idx >> 7, side = (idx >> 6) & 1, ci = idx & 63;
        int gi = i0 - 1 + r;
        int gc = jq * 32 + (side ? 32 : -1);
        hv[q] = ((unsigned)gi < 128u && (unsigned)gc < 128u)
              ? xn[((size_t)ci * 128 + gi) * 128 + gc] : 0.f;
    }
    #pragma unroll
    for (int q = 0; q < 5; ++q) {
        int idx = q * 256 + t;
        int r = idx >> 7, side = (idx >> 6) & 1, ci = idx & 63;
        xs[r][side ? 33 : 0][ci] = f2bf(hv[q]);
    }

    // A fragments + conv-bias seed, issued last (drained by barrier/compute)
    short8 af[16];
    {
        const short8* wf = (const short8*)(wfrag + wv * 8192);
        #pragma unroll
        for (int q = 0; q < 16; ++q) af[q] = wf[q * 64 + lane];
    }
    float cb[16];
    #pragma unroll
    for (int reg = 0; reg < 16; ++reg)
        cb[reg] = conv_b[(reg & 3) + 8 * (reg >> 2) + 4 * half];

    bar_lds();

    // ---- 4 compute steps: wave-local, barrier-free ----
    float osum = 0.f;
    #pragma unroll
    for (int k = 0; k < 4; ++k) {
        const int L0 = 2 * k + ph;           // rows L0, L0+1 (shared), L0+2
        f32x16 acc0, acc1;
        #pragma unroll
        for (int reg = 0; reg < 16; ++reg) { acc0[reg] = cb[reg]; acc1[reg] = cb[reg]; }
        __builtin_amdgcn_s_setprio(1);
        #pragma unroll
        for (int b = 0; b < 2; ++b) {
            int colp = ln + (pw - b) + 1;
            const short* p0 = &xs[L0][colp][half * 8];
            const short* p1 = &xs[L0 + 1][colp][half * 8];
            const short* p2 = &xs[L0 + 2][colp][half * 8];
            #pragma unroll
            for (int c = 0; c < 4; ++c) {
                short8 Fs = *(const short8*)(p1 + c * 16);   // shared middle row
                acc0 = __builtin_amdgcn_mfma_f32_32x32x16_bf16(af[4*b+c],   Fs, acc0, 0, 0, 0);
                acc1 = __builtin_amdgcn_mfma_f32_32x32x16_bf16(af[8+4*b+c], Fs, acc1, 0, 0, 0);
                short8 F0 = *(const short8*)(p0 + c * 16);
                acc0 = __builtin_amdgcn_mfma_f32_32x32x16_bf16(af[8+4*b+c], F0, acc0, 0, 0, 0);
                short8 F2 = *(const short8*)(p2 + c * 16);
                acc1 = __builtin_amdgcn_mfma_f32_32x32x16_bf16(af[4*b+c],   F2, acc1, 0, 0, 0);
            }
        }
        __builtin_amdgcn_s_setprio(0);

        // tree min-reduce over co (16 acc rows), both row-pairs
        float mn0, mn1;
        {
            float a = fminf(fminf(acc0[0], acc0[1]), fminf(acc0[2], acc0[3]));
            float b2 = fminf(fminf(acc0[4], acc0[5]), fminf(acc0[6], acc0[7]));
            float c = fminf(fminf(acc0[8], acc0[9]), fminf(acc0[10], acc0[11]));
            float d = fminf(fminf(acc0[12], acc0[13]), fminf(acc0[14], acc0[15]));
            mn0 = fminf(fminf(a, b2), fminf(c, d));
            a = fminf(fminf(acc1[0], acc1[1]), fminf(acc1[2], acc1[3]));
            b2 = fminf(fminf(acc1[4], acc1[5]), fminf(acc1[6], acc1[7]));
            c = fminf(fminf(acc1[8], acc1[9]), fminf(acc1[10], acc1[11]));
            d = fminf(fminf(acc1[12], acc1[13]), fminf(acc1[14], acc1[15]));
            mn1 = fminf(fminf(a, b2), fminf(c, d));
        }
        mn0 = fminf(mn0, __shfl_xor(mn0, 32, 64));   // fold co halves
        mn1 = fminf(mn1, __shfl_xor(mn1, 32, 64));
        osum += mn0 + mn1;                           // height-sum (linear)
    }

    if (half == 0) minbuf[wv][ln] = osum;
    bar_lds();

    // combine ph=0 + ph=1 per pw -> one strip-partial per output column
    if (t < 64) {
        int c = t & 31, pwp = t >> 5;
        float v = minbuf[pwp][c] + minbuf[2 + pwp][c];
        int ow = ((jq * 32 + c) << 1) | pwp;
        __hip_atomic_store(&partials[(size_t)st * 4096 + n * 256 + ow], v,
                           __ATOMIC_RELAXED, __HIP_MEMORY_SCOPE_AGENT);
    }
    __threadfence();     // release: partials visible at agent scope
    __syncthreads();     // all 64 storing threads done before the count
    if (t == 0) lastf = (atomicAdd(&ctr[n], 1u) == 63u) ? 1u : 0u;
    __syncthreads();

    // 64th block of image n: sum 16 strips, GELU+bias, write out[n]
    if (lastf) {
        __threadfence();
        float b0 = bias[0];
        float s = 0.f;
        #pragma unroll
        for (int s2 = 0; s2 < 16; ++s2)
            s += __hip_atomic_load(&partials[(size_t)s2 * 4096 + n * 256 + t],
                                   __ATOMIC_RELAXED, __HIP_MEMORY_SCOPE_AGENT);
        float u = 0.7978845608028654f * (s + 0.044715f * s * s * s);
        out[n * 256 + t] = 0.5f * s * (1.f + tanhf(u)) + b0;
    }
}

extern "C" void kernel_launch(void* const* d_in, const int* in_sizes, int n_in,
                              void* d_out, int out_size, void* d_ws, size_t ws_size,
                              hipStream_t stream) {
    const float* x      = (const float*)d_in[0];   // [16,64,128,128]
    const float* w      = (const float*)d_in[1];   // [64,32,4,4]
    const float* conv_b = (const float*)d_in[2];   // [32]
    const float* bias   = (const float*)d_in[3];   // [1]
    float* out = (float*)d_out;                    // 16*256

    short*    wfrag    = (short*)d_ws;                      // 64 KB
    float*    partials = (float*)((char*)d_ws + 65536);     // 256 KB
    unsigned* ctr      = (unsigned*)((char*)d_ws + 65536 + 262144);  // 64 B

    hipLaunchKernelGGL(prep, dim3(129), dim3(256), 0, stream, w, wfrag, ctr);
    hipLaunchKernelGGL(convt_mfma, dim3(16 * 16 * 4), dim3(256), 0, stream,
                       x, wfrag, conv_b, partials, ctr, bias, out);
}

// Round 7
// 113.678 us; speedup vs baseline: 1.7809x; 1.7809x over previous
//
#include <hip/hip_runtime.h>
#include <math.h>

typedef __attribute__((ext_vector_type(8))) short short8;
typedef __attribute__((ext_vector_type(16))) float f32x16;
typedef __attribute__((ext_vector_type(2))) unsigned uintx2;

#define XS_STRIDE 72   // shorts per (row,col) cell: 64 ci + 8 pad -> 144 B, 16B-aligned
#define NROWS 10       // rows staged per strip: i0-1 .. i0+8

__device__ __forceinline__ short f2bf(float f) {
    union { float f; unsigned u; } v; v.f = f;
    unsigned r = (v.u + 0x7FFFu + ((v.u >> 16) & 1u)) >> 16;
    return (short)r;
}

// packed f32x2 -> bf16x2 (RNE on gfx950)
__device__ __forceinline__ unsigned cvt_pk_bf16(float lo, float hi) {
    unsigned r;
    asm("v_cvt_pk_bf16_f32 %0, %1, %2" : "=v"(r) : "v"(lo), "v"(hi));
    return r;
}

// Barrier draining LDS ops only (no vmcnt(0) like __syncthreads).
__device__ __forceinline__ void bar_lds() {
    asm volatile("s_waitcnt lgkmcnt(0)" ::: "memory");
    __builtin_amdgcn_s_barrier();
}

// Build weight A-fragments (wfrag[p][q][lane][j], p=ph*2+pw, q=tap*4+ci_blk);
// tail block zeroes the accumulator and the 16 per-image counters.
__global__ void prep(const float* __restrict__ w, short* __restrict__ wfrag,
                     float* __restrict__ acc, unsigned* __restrict__ ctr) {
    if (blockIdx.x >= 128) {
        #pragma unroll
        for (int i = 0; i < 16; ++i) acc[i * 256 + threadIdx.x] = 0.f;
        if (threadIdx.x < 16) ctr[threadIdx.x] = 0u;
        return;
    }
    int idx = blockIdx.x * 256 + threadIdx.x;   // 0 .. 32767
    int j    = idx & 7;
    int lane = (idx >> 3) & 63;
    int q    = (idx >> 9) & 15;
    int p    = idx >> 13;
    int co = lane & 31, hf = lane >> 5;
    int ci = (q & 3) * 16 + hf * 8 + j;
    int tq = q >> 2, a = tq >> 1, b = tq & 1;
    int ph = p >> 1, pw = p & 1;
    int kh = 2 * a + 1 - ph, kw = 2 * b + 1 - pw;
    wfrag[idx] = f2bf(w[((ci * 32 + co) * 4 + kh) * 4 + kw]);
}

// Block = (n, col quarter jq [32 cols], row strip st [8 input rows]).
// Staging (FIFO-aware order): core rows depth-2 pipeline FIRST, halo
// gathers AFTER all core loads (vmcnt retires in order - gathers no longer
// block core writes), af/cb last. One LDS barrier, then the barrier-free
// 4-step MFMA body (both row-pairs interleaved, shared middle row).
// Epilogue: device-scope atomicAdd partial column sums into acc (coherent
// at IF$, NO fence), per-image counter; 64th block of each image applies
// GELU+bias (fused finalize, agent-scope loads).
__global__ __launch_bounds__(256, 3) void convt_mfma(
    const float* __restrict__ x, const short* __restrict__ wfrag,
    const float* __restrict__ conv_b, float* __restrict__ acc,
    unsigned* __restrict__ ctr, const float* __restrict__ bias,
    float* __restrict__ out)
{
    __shared__ short xs[NROWS][34][XS_STRIDE];   // 48,960 B
    __shared__ float minbuf[4][32];
    __shared__ unsigned lastf;

    // XCD-aware bijective swizzle (1024 % 8 == 0)
    int blk = ((blockIdx.x & 7) << 7) | (blockIdx.x >> 3);
    const int jq = blk & 3, st = (blk >> 2) & 15, n = blk >> 6;
    const int t  = threadIdx.x;
    const int i0 = st * 8;

    const int wv = t >> 6, lane = t & 63;    // wave = output parity (ph,pw)
    const int ph = wv >> 1, pw = wv & 1;
    const int ln = lane & 31, half = lane >> 5;

    const float* xn = x + (size_t)n * 64 * 128 * 128;
    const int col  = t & 31;
    const int cib  = (t >> 5) * 8;
    const int gcol = jq * 32 + col;

    // ---- staging: core rows first, depth-2 pipeline (R3-proven pressure) ----
    float pfA[8], pfB[8];
    auto load_row = [&](int r, float* dst) {
        int gi = i0 - 1 + r;
        bool rowok = (unsigned)gi < 128u;
        int gic = rowok ? gi : 0;
        const float* px = xn + ((size_t)cib * 128 + gic) * 128 + gcol;
        #pragma unroll
        for (int c = 0; c < 8; ++c) dst[c] = rowok ? px[c * 16384] : 0.f;
    };
    auto write_row = [&](int r, const float* src) {
        uintx2 u0, u1;
        u0.x = cvt_pk_bf16(src[0], src[1]); u0.y = cvt_pk_bf16(src[2], src[3]);
        u1.x = cvt_pk_bf16(src[4], src[5]); u1.y = cvt_pk_bf16(src[6], src[7]);
        *(uintx2*)&xs[r][col + 1][cib]     = u0;
        *(uintx2*)&xs[r][col + 1][cib + 4] = u1;
    };
    load_row(0, pfA);
    load_row(1, pfB);
    #pragma unroll
    for (int r = 0; r < NROWS; r += 2) {
        write_row(r, pfA);
        if (r + 2 < NROWS) load_row(r + 2, pfA);
        write_row(r + 1, pfB);
        if (r + 3 < NROWS) load_row(r + 3, pfB);
    }

    // halo gathers (10 rows x 2 sides x 64 ci) AFTER all core loads
    float hv[5];
    #pragma unroll
    for (int q = 0; q < 5; ++q) {
        int idx = q * 256 + t;
        int r = idx >> 7, side = (idx >> 6) & 1, ci = idx & 63;
        int gi = i0 - 1 + r;
        int gc = jq * 32 + (side ? 32 : -1);
        hv[q] = ((unsigned)gi < 128u && (unsigned)gc < 128u)
              ? xn[((size_t)ci * 128 + gi) * 128 + gc] : 0.f;
    }
    #pragma unroll
    for (int q = 0; q < 5; ++q) {
        int idx = q * 256 + t;
        int r = idx >> 7, side = (idx >> 6) & 1, ci = idx & 63;
        xs[r][side ? 33 : 0][ci] = f2bf(hv[q]);
    }

    // A fragments + conv-bias seed, issued last
    short8 af[16];
    {
        const short8* wf = (const short8*)(wfrag + wv * 8192);
        #pragma unroll
        for (int q = 0; q < 16; ++q) af[q] = wf[q * 64 + lane];
    }
    float cb[16];
    #pragma unroll
    for (int reg = 0; reg < 16; ++reg)
        cb[reg] = conv_b[(reg & 3) + 8 * (reg >> 2) + 4 * half];

    bar_lds();

    // ---- 4 compute steps: wave-local, barrier-free ----
    float osum = 0.f;
    #pragma unroll
    for (int k = 0; k < 4; ++k) {
        const int L0 = 2 * k + ph;           // rows L0, L0+1 (shared), L0+2
        f32x16 acc0, acc1;
        #pragma unroll
        for (int reg = 0; reg < 16; ++reg) { acc0[reg] = cb[reg]; acc1[reg] = cb[reg]; }
        __builtin_amdgcn_s_setprio(1);
        #pragma unroll
        for (int b = 0; b < 2; ++b) {
            int colp = ln + (pw - b) + 1;
            const short* p0 = &xs[L0][colp][half * 8];
            const short* p1 = &xs[L0 + 1][colp][half * 8];
            const short* p2 = &xs[L0 + 2][colp][half * 8];
            #pragma unroll
            for (int c = 0; c < 4; ++c) {
                short8 Fs = *(const short8*)(p1 + c * 16);   // shared middle row
                acc0 = __builtin_amdgcn_mfma_f32_32x32x16_bf16(af[4*b+c],   Fs, acc0, 0, 0, 0);
                acc1 = __builtin_amdgcn_mfma_f32_32x32x16_bf16(af[8+4*b+c], Fs, acc1, 0, 0, 0);
                short8 F0 = *(const short8*)(p0 + c * 16);
                acc0 = __builtin_amdgcn_mfma_f32_32x32x16_bf16(af[8+4*b+c], F0, acc0, 0, 0, 0);
                short8 F2 = *(const short8*)(p2 + c * 16);
                acc1 = __builtin_amdgcn_mfma_f32_32x32x16_bf16(af[4*b+c],   F2, acc1, 0, 0, 0);
            }
        }
        __builtin_amdgcn_s_setprio(0);

        // tree min-reduce over co (16 acc rows), both row-pairs
        float mn0, mn1;
        {
            float a = fminf(fminf(acc0[0], acc0[1]), fminf(acc0[2], acc0[3]));
            float b2 = fminf(fminf(acc0[4], acc0[5]), fminf(acc0[6], acc0[7]));
            float c = fminf(fminf(acc0[8], acc0[9]), fminf(acc0[10], acc0[11]));
            float d = fminf(fminf(acc0[12], acc0[13]), fminf(acc0[14], acc0[15]));
            mn0 = fminf(fminf(a, b2), fminf(c, d));
            a = fminf(fminf(acc1[0], acc1[1]), fminf(acc1[2], acc1[3]));
            b2 = fminf(fminf(acc1[4], acc1[5]), fminf(acc1[6], acc1[7]));
            c = fminf(fminf(acc1[8], acc1[9]), fminf(acc1[10], acc1[11]));
            d = fminf(fminf(acc1[12], acc1[13]), fminf(acc1[14], acc1[15]));
            mn1 = fminf(fminf(a, b2), fminf(c, d));
        }
        mn0 = fminf(mn0, __shfl_xor(mn0, 32, 64));   // fold co halves
        mn1 = fminf(mn1, __shfl_xor(mn1, 32, 64));
        osum += mn0 + mn1;                           // height-sum (linear)
    }

    if (half == 0) minbuf[wv][ln] = osum;
    bar_lds();

    // combine ph=0 + ph=1 per pw -> one device-scope atomicAdd per column
    // (coherent at IF$ by construction: no threadfence / L2 writeback needed)
    if (t < 64) {
        int c = t & 31, pwp = t >> 5;
        float v = minbuf[pwp][c] + minbuf[2 + pwp][c];
        int ow = ((jq * 32 + c) << 1) | pwp;
        atomicAdd(&acc[n * 256 + ow], v);
    }
    __syncthreads();    // drains each wave's vmcnt(0): atomics globally done
    if (t == 0) lastf = (atomicAdd(&ctr[n], 1u) == 63u) ? 1u : 0u;
    __syncthreads();

    // 64th block of image n: GELU+bias on its 256 sums (fused finalize)
    if (lastf) {
        __threadfence();   // acquire (single block only - cost negligible)
        float s = __hip_atomic_load(&acc[n * 256 + t], __ATOMIC_RELAXED,
                                    __HIP_MEMORY_SCOPE_AGENT);
        float u = 0.7978845608028654f * (s + 0.044715f * s * s * s);
        out[n * 256 + t] = 0.5f * s * (1.f + tanhf(u)) + bias[0];
    }
}

extern "C" void kernel_launch(void* const* d_in, const int* in_sizes, int n_in,
                              void* d_out, int out_size, void* d_ws, size_t ws_size,
                              hipStream_t stream) {
    const float* x      = (const float*)d_in[0];   // [16,64,128,128]
    const float* w      = (const float*)d_in[1];   // [64,32,4,4]
    const float* conv_b = (const float*)d_in[2];   // [32]
    const float* bias   = (const float*)d_in[3];   // [1]
    float* out = (float*)d_out;                    // 16*256

    short*    wfrag = (short*)d_ws;                          // 64 KB
    float*    acc   = (float*)((char*)d_ws + 65536);         // 16 KB
    unsigned* ctr   = (unsigned*)((char*)d_ws + 65536 + 16384);  // 64 B

    hipLaunchKernelGGL(prep, dim3(129), dim3(256), 0, stream, w, wfrag, acc, ctr);
    hipLaunchKernelGGL(convt_mfma, dim3(16 * 16 * 4), dim3(256), 0, stream,
                       x, wfrag, conv_b, acc, ctr, bias, out);
}